// Round 11
// baseline (101.541 us; speedup 1.0000x reference)
//
#include <hip/hip_runtime.h>
#include <hip/hip_bf16.h>

// B=1, S=4096, D=4096, O=4096
//   q = fake-quant(x) per row (int8 levels, scale = 127/max(|x|,1e-5))
//   out[s,o] = (sum_d qi[s,d]*W[o,d]) * rscale[s]/ws + bias[o]/ws
// qi in [-128,127], W in {-1,0,1}: i8 MFMA with i32 accum is EXACT (|sum|<2^19).
//
// R11 = R3/R10 ring-4 skeleton + mfma_i32_32x32x32_i8 (+12% rate, half the
// MFMA instructions) + OPERAND-LINEAR LDS layout: each MFMA instruction's 64
// lane-fragments stored contiguously -> ds_read_b128 addr = base + lane*16,
// conflict-free by construction (no swizzle). Staging permutation moved to
// the per-lane global source (linear gload_lds dest, rule #21).

#define SEQ  4096
#define DIM  4096
#define OUTD 4096

typedef int i32x4 __attribute__((ext_vector_type(4)));
typedef int i32x16 __attribute__((ext_vector_type(16)));
typedef unsigned char u8;

__device__ __forceinline__ void gload16(const void* g, void* lds) {
    __builtin_amdgcn_global_load_lds(
        (const __attribute__((address_space(1))) void*)g,
        (__attribute__((address_space(3))) void*)lds, 16, 0, 0);
}

// ---------------- Kernel 1: fused prep (quant rows | W conversion) ----------------
__global__ __launch_bounds__(256) void prep_kernel(
    const float* __restrict__ x, char* __restrict__ q, float* __restrict__ rscale,
    const float4* __restrict__ W4, char4* __restrict__ Wb4) {
    const int bid = blockIdx.x;
    const int t = threadIdx.x;
    if (bid < SEQ) {
        const int row = bid;
        const int lane = t & 63, wave = t >> 6;
        const float4* xr = (const float4*)(x + (size_t)row * DIM);
        float4 r[4];
        float m = 0.0f;
#pragma unroll
        for (int i = 0; i < 4; ++i) {
            r[i] = xr[t + 256 * i];
            m = fmaxf(m, fmaxf(fmaxf(fabsf(r[i].x), fabsf(r[i].y)),
                               fmaxf(fabsf(r[i].z), fabsf(r[i].w))));
        }
#pragma unroll
        for (int off = 32; off > 0; off >>= 1)
            m = fmaxf(m, __shfl_xor(m, off, 64));
        __shared__ float red[4];
        if (lane == 0) red[wave] = m;
        __syncthreads();
        const float amax = fmaxf(fmaxf(red[0], red[1]), fmaxf(red[2], red[3]));
        const float scale = 127.0f / fmaxf(amax, 1e-5f);
        if (t == 0) rscale[row] = 1.0f / scale;
        char4* qr = (char4*)(q + (size_t)row * DIM);
#pragma unroll
        for (int i = 0; i < 4; ++i) {
            float q0 = fminf(127.0f, fmaxf(-128.0f, rintf(r[i].x * scale)));
            float q1 = fminf(127.0f, fmaxf(-128.0f, rintf(r[i].y * scale)));
            float q2 = fminf(127.0f, fmaxf(-128.0f, rintf(r[i].z * scale)));
            float q3 = fminf(127.0f, fmaxf(-128.0f, rintf(r[i].w * scale)));
            char4 o;
            o.x = (signed char)q0; o.y = (signed char)q1;
            o.z = (signed char)q2; o.w = (signed char)q3;
            qr[t + 256 * i] = o;
        }
    } else {
        const int n4 = (OUTD * DIM) / 4;
        int i = (bid - SEQ) * 256 + t;
        const int stride = SEQ * 256;
        for (; i < n4; i += stride) {
            float4 w = W4[i];
            char4 o;
            o.x = (signed char)w.x; o.y = (signed char)w.y;
            o.z = (signed char)w.z; o.w = (signed char)w.w;
            Wb4[i] = o;
        }
    }
}

// ---------------- Kernel 2: ring-4, 32x32x32 i8 GEMM, operand-linear LDS ----------
// Per ring slot, per matrix: 2 chunks of 8KB (128 rows x 64B each).
// Chunk layout: element (r, 16B-quarter qq) at byte
//   (r>>5)*2048 + (qq>>1)*1024 + (qq&1)*512 + (r&31)*16
// -> MFMA operand (32-row block b, K-step s, K-half kh) occupies the
//    contiguous 1024B [b*2048 + s*1024 + kh*512 ...], lane-linear.
__global__ __launch_bounds__(512, 2) void gemm_kernel(
    const u8* __restrict__ A, const u8* __restrict__ B,
    const float* __restrict__ rscale, const float* __restrict__ bias,
    const float* __restrict__ wscale, float* __restrict__ out) {
    __shared__ __align__(16) u8 As[4 * 16384];   // 4 slots x (2 chunks x 8KB)
    __shared__ __align__(16) u8 Bs[4 * 16384];
    const int tid = threadIdx.x;
    const int lane = tid & 63, wave = tid >> 6;
    const int wr = wave >> 2, wc = wave & 3;       // 2 x 4 waves, 128x64 per wave
    const int cl = lane & 31;                      // fragment row/col lane
    const int kh = lane >> 5;                      // K-half within 32B K-step

    // bijective XCD swizzle (256 % 8 == 0)
    const int bid = blockIdx.x;
    const int swz = (bid & 7) * 32 + (bid >> 3);
    const int brow = swz >> 4, bcol = swz & 15;

    // staging inverse map: thread t fills LDS slot t (16B) of each 8KB chunk;
    // slot t <-> (row rt, quarter qt): t = b*128 + s*64 + kh*32 + i
    const int rt = ((tid >> 7) << 5) + (tid & 31); // 0..127
    const int kbt = ((tid >> 5) & 3) * 16;         // quarter byte offset
    const u8* gA0 = A + (size_t)(brow * 256 + rt) * DIM + kbt;
    const u8* gA1 = A + (size_t)(brow * 256 + 128 + rt) * DIM + kbt;
    const u8* gB0 = B + (size_t)(bcol * 256 + rt) * DIM + kbt;
    const u8* gB1 = B + (size_t)(bcol * 256 + 128 + rt) * DIM + kbt;
    u8* lA0 = &As[tid * 16];
    u8* lA1 = &As[8192 + tid * 16];
    u8* lB0 = &Bs[tid * 16];
    u8* lB1 = &Bs[8192 + tid * 16];

#define STAGE(T, S) do { const int _k = (T) * 64;          \
        gload16(gA0 + _k, lA0 + (S) * 16384);              \
        gload16(gA1 + _k, lA1 + (S) * 16384);              \
        gload16(gB0 + _k, lB0 + (S) * 16384);              \
        gload16(gB1 + _k, lB1 + (S) * 16384); } while (0)

    // fragment offsets: A block m (chunk wr), B block wc*2+n (chunk bb>>2)
    int aoff[4][2], boff[2][2];
#pragma unroll
    for (int m = 0; m < 4; ++m)
#pragma unroll
        for (int s = 0; s < 2; ++s)
            aoff[m][s] = wr * 8192 + m * 2048 + s * 1024 + kh * 512 + cl * 16;
#pragma unroll
    for (int n = 0; n < 2; ++n)
#pragma unroll
        for (int s = 0; s < 2; ++s) {
            const int bb = wc * 2 + n;             // 0..7
            boff[n][s] = (bb >> 2) * 8192 + (bb & 3) * 2048 + s * 1024
                         + kh * 512 + cl * 16;
        }

    i32x16 acc[4][2] = {};

#define COMPUTE(S) do {                                                        \
        i32x4 af[4][2], bfv[2][2];                                             \
        _Pragma("unroll")                                                      \
        for (int s = 0; s < 2; ++s) {                                          \
            _Pragma("unroll")                                                  \
            for (int n = 0; n < 2; ++n)                                        \
                bfv[n][s] = *(const i32x4*)&Bs[(S) * 16384 + boff[n][s]];      \
            _Pragma("unroll")                                                  \
            for (int m = 0; m < 4; ++m)                                        \
                af[m][s] = *(const i32x4*)&As[(S) * 16384 + aoff[m][s]];       \
        }                                                                      \
        _Pragma("unroll")                                                      \
        for (int s = 0; s < 2; ++s)                                            \
            _Pragma("unroll")                                                  \
            for (int m = 0; m < 4; ++m)                                        \
                _Pragma("unroll")                                              \
                for (int n = 0; n < 2; ++n)                                    \
                    acc[m][n] = __builtin_amdgcn_mfma_i32_32x32x32_i8(         \
                        af[m][s], bfv[n][s], acc[m][n], 0, 0, 0);              \
    } while (0)

#define VMW(N) asm volatile("s_waitcnt vmcnt(" #N ")" ::: "memory")
#define BAR()  do { asm volatile("" ::: "memory");                             \
                    __builtin_amdgcn_s_barrier();                              \
                    asm volatile("" ::: "memory"); } while (0)

    // 64 K-tiles of BK=64. Prologue: tiles 0..2 in flight.
    STAGE(0, 0); STAGE(1, 1); STAGE(2, 2);

    for (int tb = 0; tb < 15; ++tb) {
        const int t = tb * 4;
        VMW(8); BAR(); STAGE(t + 3, 3); COMPUTE(0);
        VMW(8); BAR(); STAGE(t + 4, 0); COMPUTE(1);
        VMW(8); BAR(); STAGE(t + 5, 1); COMPUTE(2);
        VMW(8); BAR(); STAGE(t + 6, 2); COMPUTE(3);
    }
    // tail: tiles 60..63
    VMW(8); BAR(); STAGE(63, 3); COMPUTE(0);
    VMW(8); BAR(); COMPUTE(1);
    VMW(4); BAR(); COMPUTE(2);
    VMW(0); BAR(); COMPUTE(3);

    // epilogue: 32x32 C/D layout col=lane&31, row=(reg&3)+8*(reg>>2)+4*(lane>>5)
    // (pass-verified in R4, absmax 1.0)
    const float invws = 1.0f / wscale[0];
    const int rr0 = brow * 256 + wr * 128 + kh * 4;
    const int c0 = bcol * 256 + wc * 64 + cl;
    float bv[2];
#pragma unroll
    for (int n = 0; n < 2; ++n) bv[n] = bias[c0 + n * 32] * invws;
#pragma unroll
    for (int m = 0; m < 4; ++m) {
#pragma unroll
        for (int qg = 0; qg < 4; ++qg) {
#pragma unroll
            for (int j = 0; j < 4; ++j) {
                const int r = rr0 + m * 32 + qg * 8 + j;
                const int reg = qg * 4 + j;
                const float rs = rscale[r] * invws;
                float* orow = out + (size_t)r * OUTD + c0;
#pragma unroll
                for (int n = 0; n < 2; ++n)
                    orow[n * 32] = (float)acc[m][n][reg] * rs + bv[n];
            }
        }
    }
#undef STAGE
#undef COMPUTE
#undef VMW
#undef BAR
}

extern "C" void kernel_launch(void* const* d_in, const int* in_sizes, int n_in,
                              void* d_out, int out_size, void* d_ws, size_t ws_size,
                              hipStream_t stream) {
    const float* x      = (const float*)d_in[0];
    const float* W      = (const float*)d_in[1];
    const float* bias   = (const float*)d_in[2];
    const float* wscale = (const float*)d_in[3];
    float* out = (float*)d_out;

    char* ws = (char*)d_ws;
    char* q_i8 = ws;                                   // 16 MB
    char* w_i8 = ws + (size_t)16777216;                // 16 MB
    float* rscale = (float*)(ws + (size_t)33554432);   // 16 KB

    prep_kernel<<<SEQ + 4096, 256, 0, stream>>>(
        x, q_i8, rscale, (const float4*)W, (char4*)w_i8);
    gemm_kernel<<<256, 512, 0, stream>>>((const u8*)q_i8, (const u8*)w_i8,
                                         rscale, bias, wscale, out);
}